// Round 1
// baseline (217.231 us; speedup 1.0000x reference)
//
#include <hip/hip_runtime.h>
#include <hip/hip_bf16.h>
#include <stdint.h>
#include <math.h>

#define NTOK 4096
#define DIM 768
#define FF 3072
#define NE 4

typedef __attribute__((ext_vector_type(8))) short bf16x8;
typedef __attribute__((ext_vector_type(4))) float f32x4;
typedef unsigned short u16;

static __device__ __forceinline__ u16 f2bf(float f) {
    union { float f; unsigned u; } c; c.f = f;
    unsigned r = (c.u + 0x7FFFu + ((c.u >> 16) & 1u)) >> 16;
    return (u16)r;
}

#define GLD_LDS16(g, l) __builtin_amdgcn_global_load_lds( \
    (const __attribute__((address_space(1))) void*)(g),   \
    (__attribute__((address_space(3))) void*)(l), 16, 0, 0)

// ---------------- gating: logits, softmax, argmax, token lists ----------------
__global__ __launch_bounds__(256) void gate_kernel(
    const float* __restrict__ x, const float* __restrict__ gw,
    float* __restrict__ probs, int* __restrict__ counts, int* __restrict__ tlist)
{
    const int wid = threadIdx.x >> 6, lane = threadIdx.x & 63;
    const int n = blockIdx.x * 4 + wid;
    const float* xr = x + (size_t)n * DIM;
    float a0 = 0.f, a1 = 0.f, a2 = 0.f, a3 = 0.f;
    for (int d = lane; d < DIM; d += 64) {
        float xv = xr[d];
        a0 += xv * gw[0 * DIM + d];
        a1 += xv * gw[1 * DIM + d];
        a2 += xv * gw[2 * DIM + d];
        a3 += xv * gw[3 * DIM + d];
    }
    #pragma unroll
    for (int off = 32; off > 0; off >>= 1) {
        a0 += __shfl_xor(a0, off);
        a1 += __shfl_xor(a1, off);
        a2 += __shfl_xor(a2, off);
        a3 += __shfl_xor(a3, off);
    }
    if (lane == 0) {
        float l[4] = {a0, a1, a2, a3};
        float m = fmaxf(fmaxf(l[0], l[1]), fmaxf(l[2], l[3]));
        float p[4], s = 0.f;
        #pragma unroll
        for (int e = 0; e < 4; e++) { p[e] = expf(l[e] - m); s += p[e]; }
        float inv = 1.f / s;
        int amax = 0; float best = l[0];
        #pragma unroll
        for (int e = 1; e < 4; e++) if (l[e] > best) { best = l[e]; amax = e; }
        #pragma unroll
        for (int e = 0; e < 4; e++) probs[n * 4 + e] = p[e] * inv;
        int pos = atomicAdd(&counts[amax], 1);
        tlist[amax * NTOK + pos] = n;
    }
}

// ---------------- balance loss + gate_load tail outputs ----------------
__global__ __launch_bounds__(256) void finalize_kernel(
    const float* __restrict__ probs, const int* __restrict__ counts,
    float* __restrict__ tail)
{
    __shared__ float sdata[256];
    float part[4] = {0.f, 0.f, 0.f, 0.f};
    for (int n = threadIdx.x; n < NTOK; n += 256) {
        #pragma unroll
        for (int e = 0; e < 4; e++) part[e] += probs[n * 4 + e];
    }
    float Ps[4] = {0.f, 0.f, 0.f, 0.f};
    for (int e = 0; e < 4; e++) {
        sdata[threadIdx.x] = part[e];
        __syncthreads();
        for (int s = 128; s > 0; s >>= 1) {
            if ((int)threadIdx.x < s) sdata[threadIdx.x] += sdata[threadIdx.x + s];
            __syncthreads();
        }
        if (threadIdx.x == 0) Ps[e] = sdata[0];
        __syncthreads();
    }
    if (threadIdx.x == 0) {
        float bl = 0.f;
        #pragma unroll
        for (int e = 0; e < 4; e++)
            bl += (Ps[e] / (float)NTOK) * ((float)counts[e] / (float)NTOK);
        bl *= (float)NE;
        tail[0] = bl;
        #pragma unroll
        for (int e = 0; e < 4; e++) tail[1 + e] = (float)counts[e];
    }
}

// ---------------- fp32 -> bf16 elementwise ----------------
__global__ __launch_bounds__(256) void convert_x_kernel(
    const float4* __restrict__ in, u16* __restrict__ out)
{
    int i = blockIdx.x * 256 + threadIdx.x;
    float4 v = in[i];
    ushort4 o;
    o.x = f2bf(v.x); o.y = f2bf(v.y); o.z = f2bf(v.z); o.w = f2bf(v.w);
    *(ushort4*)(out + (size_t)i * 4) = o;
}

// ---------------- fp32 [E][R][C] -> bf16 [E][C][R] tiled transpose ----------------
__global__ __launch_bounds__(256) void transpose_convert_kernel(
    const float* __restrict__ in, u16* __restrict__ out, int R, int C)
{
    __shared__ float tile[64][65];
    const int e = blockIdx.z;
    const float* src = in + (size_t)e * R * C;
    u16* dst = out + (size_t)e * R * C;
    const int r0 = blockIdx.y * 64, c0 = blockIdx.x * 64;
    const int col = threadIdx.x & 63, rr = threadIdx.x >> 6;
    #pragma unroll
    for (int p = 0; p < 16; ++p) {
        int row = p * 4 + rr;
        tile[row][col] = src[(size_t)(r0 + row) * C + (c0 + col)];
    }
    __syncthreads();
    #pragma unroll
    for (int p = 0; p < 16; ++p) {
        int row = p * 4 + rr;   // row within the c-block (output row)
        dst[(size_t)(c0 + row) * R + (r0 + col)] = f2bf(tile[col][row]);
    }
}

// ---------------- grouped MFMA GEMM: C[m][n] = gather(A)[m][:] @ Bt[n][:] ----------------
// A: [NTOK][KDIM] bf16 (rows gathered via token list)
// Bt: [NE][NCOL][KDIM] bf16 (pre-transposed weights)
// GELU_EP: fuse bias+gelu, write bf16 to Hout; else fuse bias, write f32 to Fout.
template <int KDIM, int NCOL, int GELU_EP>
__global__ __launch_bounds__(256) void moe_gemm(
    const u16* __restrict__ A, const u16* __restrict__ Bt,
    const float* __restrict__ bias, const int* __restrict__ counts,
    const int* __restrict__ tlist, u16* __restrict__ Hout,
    float* __restrict__ Fout)
{
    constexpr int CT = NCOL / 128;
    const int bid = blockIdx.x;
    const int e = bid / (32 * CT);
    const int rem = bid % (32 * CT);
    const int rt = rem / CT;
    const int ct = rem % CT;
    const int cnt = counts[e];
    if (rt * 128 >= cnt) return;
    const int nvalid = min(128, cnt - rt * 128);
    const int* list = tlist + e * NTOK + rt * 128;

    __shared__ __align__(16) u16 As[128 * 32];
    __shared__ __align__(16) u16 Bs[128 * 32];

    const int tid = threadIdx.x;
    const int lane = tid & 63;
    const int w = tid >> 6;

    // staging mapping: per wave, 2 calls; call c covers rows (w*2+c)*16 + (lane>>2), k = (lane&3)*8
    const int kk = (lane & 3) * 8;
    const int r0 = (w * 2 + 0) * 16 + (lane >> 2);
    const int r1 = (w * 2 + 1) * 16 + (lane >> 2);
    const int t0 = list[min(r0, nvalid - 1)];
    const int t1 = list[min(r1, nvalid - 1)];
    const u16* gA0 = A + (size_t)t0 * KDIM + kk;
    const u16* gA1 = A + (size_t)t1 * KDIM + kk;
    const u16* Be = Bt + ((size_t)e * NCOL + (size_t)ct * 128) * KDIM;
    const u16* gB0 = Be + (size_t)r0 * KDIM + kk;
    const u16* gB1 = Be + (size_t)r1 * KDIM + kk;
    u16* lA0 = As + (w * 2 + 0) * 512;
    u16* lA1 = As + (w * 2 + 1) * 512;
    u16* lB0 = Bs + (w * 2 + 0) * 512;
    u16* lB1 = Bs + (w * 2 + 1) * 512;

    const int wm = w >> 1, wn = w & 1;
    const int fr = lane & 15, fg = lane >> 4;

    f32x4 acc[4][4];
    #pragma unroll
    for (int i = 0; i < 4; i++)
        #pragma unroll
        for (int j = 0; j < 4; j++) acc[i][j] = (f32x4){0.f, 0.f, 0.f, 0.f};

    for (int k0 = 0; k0 < KDIM; k0 += 32) {
        GLD_LDS16(gA0 + k0, lA0);
        GLD_LDS16(gA1 + k0, lA1);
        GLD_LDS16(gB0 + k0, lB0);
        GLD_LDS16(gB1 + k0, lB1);
        __syncthreads();   // drains vmcnt before barrier (compiler-enforced)
        bf16x8 af[4], bg[4];
        #pragma unroll
        for (int m4 = 0; m4 < 4; m4++)
            af[m4] = *(const bf16x8*)&As[(wm * 64 + m4 * 16 + fr) * 32 + fg * 8];
        #pragma unroll
        for (int n4 = 0; n4 < 4; n4++)
            bg[n4] = *(const bf16x8*)&Bs[(wn * 64 + n4 * 16 + fr) * 32 + fg * 8];
        #pragma unroll
        for (int m4 = 0; m4 < 4; m4++)
            #pragma unroll
            for (int n4 = 0; n4 < 4; n4++)
                acc[m4][n4] = __builtin_amdgcn_mfma_f32_16x16x32_bf16(
                    af[m4], bg[n4], acc[m4][n4], 0, 0, 0);
        __syncthreads();
    }

    // epilogue: C/D layout col = lane&15, row = (lane>>4)*4 + reg
    #pragma unroll
    for (int m4 = 0; m4 < 4; m4++) {
        const int base = wm * 64 + m4 * 16 + fg * 4;
        #pragma unroll
        for (int r = 0; r < 4; r++) {
            const int rrow = base + r;
            if (rrow < nvalid) {
                const int tok = list[rrow];
                #pragma unroll
                for (int n4 = 0; n4 < 4; n4++) {
                    const int col = ct * 128 + wn * 64 + n4 * 16 + fr;
                    float v = acc[m4][n4][r] + bias[e * NCOL + col];
                    if (GELU_EP) {
                        v = 0.5f * v * (1.f + erff(v * 0.70710678118654752f));
                        Hout[(size_t)tok * NCOL + col] = f2bf(v);
                    } else {
                        Fout[(size_t)tok * NCOL + col] = v;
                    }
                }
            }
        }
    }
}

extern "C" void kernel_launch(void* const* d_in, const int* in_sizes, int n_in,
                              void* d_out, int out_size, void* d_ws, size_t ws_size,
                              hipStream_t stream) {
    const float* x  = (const float*)d_in[0];
    // d_in[1] input_ids, d_in[2] attention_mask: unused
    const float* gw = (const float*)d_in[3];
    const float* W1 = (const float*)d_in[4];
    const float* b1 = (const float*)d_in[5];
    const float* W2 = (const float*)d_in[6];
    const float* b2 = (const float*)d_in[7];
    float* out = (float*)d_out;

    char* ws = (char*)d_ws;
    size_t o = 0;
    auto alloc = [&](size_t bytes) -> void* {
        void* p = ws + o;
        o = (o + bytes + 255) & ~(size_t)255;
        return p;
    };
    u16*   xbf    = (u16*)alloc((size_t)NTOK * DIM * 2);
    u16*   W1t    = (u16*)alloc((size_t)NE * DIM * FF * 2);
    u16*   W2t    = (u16*)alloc((size_t)NE * DIM * FF * 2);
    u16*   hbuf   = (u16*)alloc((size_t)NTOK * FF * 2);
    float* probs  = (float*)alloc((size_t)NTOK * 4 * 4);
    int*   tlist  = (int*)alloc((size_t)NE * NTOK * 4);
    int*   counts = (int*)alloc(256);

    hipMemsetAsync(counts, 0, 256, stream);
    gate_kernel<<<NTOK / 4, 256, 0, stream>>>(x, gw, probs, counts, tlist);
    finalize_kernel<<<1, 256, 0, stream>>>(probs, counts, out + (size_t)NTOK * DIM);
    convert_x_kernel<<<(NTOK * DIM / 4) / 256, 256, 0, stream>>>((const float4*)x, xbf);
    transpose_convert_kernel<<<dim3(FF / 64, DIM / 64, NE), 256, 0, stream>>>(W1, W1t, DIM, FF);
    transpose_convert_kernel<<<dim3(DIM / 64, FF / 64, NE), 256, 0, stream>>>(W2, W2t, FF, DIM);
    moe_gemm<DIM, FF, 1><<<NE * 32 * (FF / 128), 256, 0, stream>>>(
        xbf, W1t, b1, counts, tlist, hbuf, nullptr);
    moe_gemm<FF, DIM, 0><<<NE * 32 * (DIM / 128), 256, 0, stream>>>(
        hbuf, W2t, b2, counts, tlist, nullptr, out);
}

// Round 2
// 196.700 us; speedup vs baseline: 1.1044x; 1.1044x over previous
//
#include <hip/hip_runtime.h>
#include <hip/hip_bf16.h>
#include <stdint.h>
#include <math.h>

#define NTOK 4096
#define DIM 768
#define FF 3072
#define NE 4

typedef __attribute__((ext_vector_type(8))) short bf16x8;
typedef __attribute__((ext_vector_type(4))) float f32x4;
typedef unsigned short u16;

static __device__ __forceinline__ u16 f2bf(float f) {
    union { float f; unsigned u; } c; c.f = f;
    unsigned r = (c.u + 0x7FFFu + ((c.u >> 16) & 1u)) >> 16;
    return (u16)r;
}

// Abramowitz-Stegun 7.1.26, |abs err| <= 1.5e-7 (beyond bf16 grain)
static __device__ __forceinline__ float fast_erff(float x) {
    float ax = fabsf(x);
    float t = 1.0f / (1.0f + 0.3275911f * ax);
    float p = ((((1.061405429f * t - 1.453152027f) * t) + 1.421413741f) * t
               - 0.284496736f) * t + 0.254829592f;
    float y = 1.0f - p * t * __expf(-ax * ax);
    return copysignf(y, x);
}

#define GLD_LDS16(g, l) __builtin_amdgcn_global_load_lds( \
    (const __attribute__((address_space(1))) void*)(g),   \
    (__attribute__((address_space(3))) void*)(l), 16, 0, 0)

// ---------------- gating: logits, softmax, argmax, token lists ----------------
__global__ __launch_bounds__(256) void gate_kernel(
    const float* __restrict__ x, const float* __restrict__ gw,
    float* __restrict__ probs, int* __restrict__ counts, int* __restrict__ tlist,
    int* __restrict__ eid)
{
    const int wid = threadIdx.x >> 6, lane = threadIdx.x & 63;
    const int n = blockIdx.x * 4 + wid;
    const float* xr = x + (size_t)n * DIM;
    float a0 = 0.f, a1 = 0.f, a2 = 0.f, a3 = 0.f;
    for (int d = lane; d < DIM; d += 64) {
        float xv = xr[d];
        a0 += xv * gw[0 * DIM + d];
        a1 += xv * gw[1 * DIM + d];
        a2 += xv * gw[2 * DIM + d];
        a3 += xv * gw[3 * DIM + d];
    }
    #pragma unroll
    for (int off = 32; off > 0; off >>= 1) {
        a0 += __shfl_xor(a0, off);
        a1 += __shfl_xor(a1, off);
        a2 += __shfl_xor(a2, off);
        a3 += __shfl_xor(a3, off);
    }
    if (lane == 0) {
        float l[4] = {a0, a1, a2, a3};
        float m = fmaxf(fmaxf(l[0], l[1]), fmaxf(l[2], l[3]));
        float p[4], s = 0.f;
        #pragma unroll
        for (int e = 0; e < 4; e++) { p[e] = expf(l[e] - m); s += p[e]; }
        float inv = 1.f / s;
        int amax = 0; float best = l[0];
        #pragma unroll
        for (int e = 1; e < 4; e++) if (l[e] > best) { best = l[e]; amax = e; }
        #pragma unroll
        for (int e = 0; e < 4; e++) probs[n * 4 + e] = p[e] * inv;
        eid[n] = amax;
        int pos = atomicAdd(&counts[amax], 1);
        tlist[amax * NTOK + pos] = n;
    }
}

// ---------------- balance loss + gate_load tail outputs ----------------
__global__ __launch_bounds__(256) void finalize_kernel(
    const float4* __restrict__ probs4, const int* __restrict__ counts,
    float* __restrict__ tail)
{
    __shared__ float sdata[256 * 4];
    float p0 = 0.f, p1 = 0.f, p2 = 0.f, p3 = 0.f;
    for (int n = threadIdx.x; n < NTOK; n += 256) {
        float4 v = probs4[n];
        p0 += v.x; p1 += v.y; p2 += v.z; p3 += v.w;
    }
    sdata[threadIdx.x * 4 + 0] = p0;
    sdata[threadIdx.x * 4 + 1] = p1;
    sdata[threadIdx.x * 4 + 2] = p2;
    sdata[threadIdx.x * 4 + 3] = p3;
    __syncthreads();
    for (int s = 128; s > 0; s >>= 1) {
        if ((int)threadIdx.x < s) {
            #pragma unroll
            for (int e = 0; e < 4; e++)
                sdata[threadIdx.x * 4 + e] += sdata[(threadIdx.x + s) * 4 + e];
        }
        __syncthreads();
    }
    if (threadIdx.x == 0) {
        float bl = 0.f;
        #pragma unroll
        for (int e = 0; e < 4; e++)
            bl += (sdata[e] / (float)NTOK) * ((float)counts[e] / (float)NTOK);
        bl *= (float)NE;
        tail[0] = bl;
        #pragma unroll
        for (int e = 0; e < 4; e++) tail[1 + e] = (float)counts[e];
    }
}

// ---------------- fp32 -> bf16 elementwise ----------------
__global__ __launch_bounds__(256) void convert_x_kernel(
    const float4* __restrict__ in, u16* __restrict__ out)
{
    int i = blockIdx.x * 256 + threadIdx.x;
    float4 v = in[i];
    ushort4 o;
    o.x = f2bf(v.x); o.y = f2bf(v.y); o.z = f2bf(v.z); o.w = f2bf(v.w);
    *(ushort4*)(out + (size_t)i * 4) = o;
}

// ---------------- fp32 [E][R][C] -> bf16 [E][C][R] tiled transpose ----------------
__global__ __launch_bounds__(256) void transpose_convert_kernel(
    const float* __restrict__ in, u16* __restrict__ out, int R, int C)
{
    __shared__ float tile[64][65];
    const int e = blockIdx.z;
    const float* src = in + (size_t)e * R * C;
    u16* dst = out + (size_t)e * R * C;
    const int r0 = blockIdx.y * 64, c0 = blockIdx.x * 64;
    const int col = threadIdx.x & 63, rr = threadIdx.x >> 6;
    #pragma unroll
    for (int p = 0; p < 16; ++p) {
        int row = p * 4 + rr;
        tile[row][col] = src[(size_t)(r0 + row) * C + (c0 + col)];
    }
    __syncthreads();
    #pragma unroll
    for (int p = 0; p < 16; ++p) {
        int row = p * 4 + rr;
        dst[(size_t)(c0 + row) * R + (r0 + col)] = f2bf(tile[col][row]);
    }
}

// ---------------- out := bias row per token's expert (split-K atomic base) ----------------
__global__ __launch_bounds__(256) void init_out_kernel(
    const float* __restrict__ b2, const int* __restrict__ eid,
    float4* __restrict__ out4)
{
    int idx = blockIdx.x * 256 + threadIdx.x;   // over NTOK*DIM/4
    int n = idx / (DIM / 4);
    int c = idx % (DIM / 4);
    int e = eid[n];
    out4[idx] = ((const float4*)(b2 + (size_t)e * DIM))[c];
}

// ---------------- grouped MFMA GEMM, 128x256 tile, 8 waves, 2-phase dbuf ----------------
// A: [NTOK][KD] bf16 rows gathered via tlist. Bt: [NE][NCOL][KD] bf16.
// LDS layout swizzled: element (r,c16) of tile stored at byte (r*64+c*16)^((r&7)<<4).
// GELU_EP: v=gelu(v+bias) -> bf16 Hout;  else: atomicAdd f32 into Fout (bias pre-init).
template <int KD, int NCOL, int KSPLIT, int GELU_EP>
__global__ __launch_bounds__(512, 4) void moe_gemm(
    const u16* __restrict__ A, const u16* __restrict__ Bt,
    const float* __restrict__ bias, const int* __restrict__ counts,
    const int* __restrict__ tlist, u16* __restrict__ Hout,
    float* __restrict__ Fout)
{
    constexpr int KSUB = KD / KSPLIT;
    constexpr int NSTEP = KSUB / 32;
    constexpr int CTN = NCOL / 256;

    const int bid = blockIdx.x;
    const int rt = bid / (NE * CTN * KSPLIT);
    int rem = bid % (NE * CTN * KSPLIT);
    const int e = rem / (CTN * KSPLIT);
    rem %= CTN * KSPLIT;
    const int ct = rem / KSPLIT;
    const int ks = rem % KSPLIT;

    const int cnt = counts[e];
    if (rt * 128 >= cnt) return;
    const int nvalid = min(128, cnt - rt * 128);
    const int* list = tlist + e * NTOK + rt * 128;

    __shared__ __align__(16) u16 As[2][128 * 32];
    __shared__ __align__(16) u16 Bs[2][256 * 32];

    const int tid = threadIdx.x;
    const int lane = tid & 63;
    const int w = tid >> 6;

    // ---- staging source pointers (inverse-swizzled per-lane global addresses) ----
    // slot q=tid covers LDS byte q*16 of As / first half of Bs; q=tid+512 second half of Bs
    const int rp = tid >> 2, cp = tid & 3;
    const int r = rp ^ ((rp >> 2) & 1);        // unswizzled tile row
    const int c = cp ^ (r & 3);                // unswizzled 16B k-chunk
    const int tokA = list[min(r, nvalid - 1)];
    const u16* pA = A + (size_t)tokA * KD + ks * KSUB + c * 8;
    const u16* pB0 = Bt + ((size_t)e * NCOL + (size_t)(ct * 256 + r)) * KD + ks * KSUB + c * 8;
    const u16* pB1 = pB0 + (size_t)128 * KD;

    // wave-uniform LDS staging bases (HW adds lane*16)
    u16* ldsA = &As[0][0] + w * 512;
    u16* ldsB0 = &Bs[0][0] + w * 512;
    u16* ldsB1 = &Bs[0][0] + 4096 + w * 512;
    constexpr int BUFA = 128 * 32;   // u16 per As buffer
    constexpr int BUFB = 256 * 32;

    const int wm = w >> 2, wn = w & 3;          // 2 x 4 wave grid
    const int fr = lane & 15, fg = lane >> 4;
    // per-lane swizzled read offset (bytes), rows add wm*4096 + m4*1024 on top
    const int laneoff = (fr * 64 + fg * 16) ^ ((fr & 7) << 4);

    f32x4 acc[4][4];
    #pragma unroll
    for (int i = 0; i < 4; i++)
        #pragma unroll
        for (int j = 0; j < 4; j++) acc[i][j] = (f32x4){0.f, 0.f, 0.f, 0.f};

    // prologue: stage tile 0 into buffer 0
    GLD_LDS16(pA, ldsA);
    GLD_LDS16(pB0, ldsB0);
    GLD_LDS16(pB1, ldsB1);
    __syncthreads();

    int cur = 0;
    for (int t = 0; t < NSTEP; ++t) {
        if (t + 1 < NSTEP) {
            const int nb = cur ^ 1;
            const int koff = (t + 1) * 32;
            GLD_LDS16(pA + koff, ldsA + nb * BUFA);
            GLD_LDS16(pB0 + koff, ldsB0 + nb * BUFB);
            GLD_LDS16(pB1 + koff, ldsB1 + nb * BUFB);
        }
        const char* Ab = (const char*)&As[cur][0];
        const char* Bb = (const char*)&Bs[cur][0];
        bf16x8 af[4], bg[4];
        #pragma unroll
        for (int m4 = 0; m4 < 4; m4++)
            af[m4] = *(const bf16x8*)(Ab + wm * 4096 + m4 * 1024 + laneoff);
        #pragma unroll
        for (int n4 = 0; n4 < 4; n4++)
            bg[n4] = *(const bf16x8*)(Bb + wn * 4096 + n4 * 1024 + laneoff);
        #pragma unroll
        for (int m4 = 0; m4 < 4; m4++)
            #pragma unroll
            for (int n4 = 0; n4 < 4; n4++)
                acc[m4][n4] = __builtin_amdgcn_mfma_f32_16x16x32_bf16(
                    af[m4], bg[n4], acc[m4][n4], 0, 0, 0);
        __syncthreads();   // drains prefetch vmcnt + lgkm; next buffer ready
        cur ^= 1;
    }

    // ---- epilogue: C/D layout col = lane&15 (fr), row = fg*4 + reg ----
    #pragma unroll
    for (int m4 = 0; m4 < 4; m4++) {
        const int rowbase = wm * 64 + m4 * 16 + fg * 4;
        #pragma unroll
        for (int r2 = 0; r2 < 4; r2++) {
            const int row = rowbase + r2;
            if (row < nvalid) {
                const int tok = list[row];
                #pragma unroll
                for (int n4 = 0; n4 < 4; n4++) {
                    const int col = ct * 256 + wn * 64 + n4 * 16 + fr;
                    float v = acc[m4][n4][r2];
                    if (GELU_EP) {
                        v += bias[e * NCOL + col];
                        v = 0.5f * v * (1.f + fast_erff(v * 0.70710678118654752f));
                        Hout[(size_t)tok * NCOL + col] = f2bf(v);
                    } else {
                        atomicAdd(&Fout[(size_t)tok * NCOL + col], v);
                    }
                }
            }
        }
    }
}

extern "C" void kernel_launch(void* const* d_in, const int* in_sizes, int n_in,
                              void* d_out, int out_size, void* d_ws, size_t ws_size,
                              hipStream_t stream) {
    const float* x  = (const float*)d_in[0];
    const float* gw = (const float*)d_in[3];
    const float* W1 = (const float*)d_in[4];
    const float* b1 = (const float*)d_in[5];
    const float* W2 = (const float*)d_in[6];
    const float* b2 = (const float*)d_in[7];
    float* out = (float*)d_out;

    char* ws = (char*)d_ws;
    size_t o = 0;
    auto alloc = [&](size_t bytes) -> void* {
        void* p = ws + o;
        o = (o + bytes + 255) & ~(size_t)255;
        return p;
    };
    u16*   xbf    = (u16*)alloc((size_t)NTOK * DIM * 2);
    u16*   W1t    = (u16*)alloc((size_t)NE * DIM * FF * 2);
    u16*   W2t    = (u16*)alloc((size_t)NE * DIM * FF * 2);
    u16*   hbuf   = (u16*)alloc((size_t)NTOK * FF * 2);
    float* probs  = (float*)alloc((size_t)NTOK * 4 * 4);
    int*   tlist  = (int*)alloc((size_t)NE * NTOK * 4);
    int*   eid    = (int*)alloc((size_t)NTOK * 4);
    int*   counts = (int*)alloc(256);

    hipMemsetAsync(counts, 0, 256, stream);
    gate_kernel<<<NTOK / 4, 256, 0, stream>>>(x, gw, probs, counts, tlist, eid);
    finalize_kernel<<<1, 256, 0, stream>>>((const float4*)probs, counts,
                                           out + (size_t)NTOK * DIM);
    convert_x_kernel<<<(NTOK * DIM / 4) / 256, 256, 0, stream>>>((const float4*)x, xbf);
    transpose_convert_kernel<<<dim3(FF / 64, DIM / 64, NE), 256, 0, stream>>>(W1, W1t, DIM, FF);
    transpose_convert_kernel<<<dim3(DIM / 64, FF / 64, NE), 256, 0, stream>>>(W2, W2t, FF, DIM);
    init_out_kernel<<<(NTOK * DIM / 4) / 256, 256, 0, stream>>>(b2, eid, (float4*)out);

    // GEMM1: K=768, N=3072, gelu->bf16 h.  grid = 32rt * 4e * 12ct
    moe_gemm<DIM, FF, 1, 1><<<32 * NE * (FF / 256), 512, 0, stream>>>(
        xbf, W1t, b1, counts, tlist, hbuf, nullptr);
    // GEMM2: K=3072 split 4, N=768, atomic f32 into out. grid = 32rt * 4e * 3ct * 4ks
    moe_gemm<FF, DIM, 4, 0><<<32 * NE * (DIM / 256) * 4, 512, 0, stream>>>(
        hbuf, W2t, b2, counts, tlist, nullptr, out);
}